// Round 1
// baseline (651.372 us; speedup 1.0000x reference)
//
#include <hip/hip_runtime.h>

#define LQ 5376
#define DM 128
#define NH 16
#define NL 3
#define NP 4
#define DH 8

// level geometry: H = W = 64,32,16 ; starts 0,4096,5120
__device__ __forceinline__ void q_to_level(int q, int& l, int& p, int& Hl, int& Wl,
                                           int& start, int& wshift) {
    if (q < 4096)      { l = 0; start = 0;    Hl = 64; Wl = 64; wshift = 6; }
    else if (q < 5120) { l = 1; start = 4096; Hl = 32; Wl = 32; wshift = 5; }
    else               { l = 2; start = 5120; Hl = 16; Wl = 16; wshift = 4; }
    p = q - start;
}

// ---------------- kernel 0: (B,128,HW) -> x rows (B*LQ, 128) ----------------
__global__ __launch_bounds__(256) void transpose_k(const float* __restrict__ fm,
                                                   float* __restrict__ x,
                                                   int HW, int qstart) {
    __shared__ float tile[32][33];
    const int p0 = blockIdx.x * 32;
    const int c0 = blockIdx.y * 32;
    const int b  = blockIdx.z;
    const int tx = threadIdx.x;  // 32
    const int ty = threadIdx.y;  // 8
    const float* src = fm + ((size_t)(b * DM + c0)) * HW + p0;
#pragma unroll
    for (int k = 0; k < 32; k += 8)
        tile[ty + k][tx] = src[(size_t)(ty + k) * HW + tx];
    __syncthreads();
    float* dst = x + ((size_t)(b * LQ + qstart + p0)) * DM + c0;
#pragma unroll
    for (int k = 0; k < 32; k += 8)
        dst[(size_t)(ty + k) * DM + tx] = tile[tx][ty + k];
}

// ---------------- kernel 1: value = x @ W_val + b_val ----------------
// 32 queries per block; each thread owns one output column for 16 queries.
__global__ __launch_bounds__(256) void value_proj_k(const float* __restrict__ x,
                                                    const float* __restrict__ W_val,
                                                    const float* __restrict__ b_val,
                                                    float* __restrict__ val) {
    __shared__ float xs[32][DM];
    const int t = threadIdx.x;
    const size_t gq0 = (size_t)blockIdx.x * 32;
    for (int i = t; i < 32 * DM; i += 256)
        ((float*)xs)[i] = x[gq0 * DM + i];
    __syncthreads();
    const int j  = t & 127;
    const int qb = (t >> 7) * 16;
    float acc[16];
    const float bj = b_val[j];
#pragma unroll
    for (int k = 0; k < 16; ++k) acc[k] = bj;
    for (int c = 0; c < DM; ++c) {
        const float w = W_val[c * DM + j];
#pragma unroll
        for (int k = 0; k < 16; ++k) acc[k] += xs[qb + k][c] * w;
    }
#pragma unroll
    for (int k = 0; k < 16; ++k)
        val[(gq0 + qb + k) * DM + j] = acc[k];
}

// ---------------- kernel 2: offs/attn proj + softmax + sampling + out proj ----------------
__global__ __launch_bounds__(256) void msda_main_k(const float* __restrict__ x,
                                                   const float* __restrict__ val,
                                                   const float* __restrict__ W_off,
                                                   const float* __restrict__ b_off,
                                                   const float* __restrict__ W_attn,
                                                   const float* __restrict__ b_attn,
                                                   const float* __restrict__ W_out,
                                                   const float* __restrict__ b_out,
                                                   float* __restrict__ out) {
    __shared__ float xs[16][DM];       // 8 KB
    __shared__ float offs_s[16][384];  // 24 KB
    __shared__ float attn_s[16][192];  // 12 KB
    __shared__ float oh[16][DM];       // 8 KB
    const int t = threadIdx.x;
    const int gq0 = blockIdx.x * 16;

    // phase 1: x tile -> LDS
    for (int i = t; i < 16 * DM; i += 256)
        ((float*)xs)[i] = x[(size_t)gq0 * DM + i];
    __syncthreads();

    // phase 2: offs (384) + attn (192) projections; per-column register reuse over 16 queries
    for (int j = t; j < 576; j += 256) {
        const float* Wp;
        int ncol, col;
        float bias;
        if (j < 384) { Wp = W_off;  ncol = 384; col = j;       bias = b_off[col]; }
        else         { Wp = W_attn; ncol = 192; col = j - 384; bias = b_attn[col]; }
        float acc[16];
#pragma unroll
        for (int k = 0; k < 16; ++k) acc[k] = bias;
        for (int c = 0; c < DM; ++c) {
            const float w = Wp[c * ncol + col];
#pragma unroll
            for (int k = 0; k < 16; ++k) acc[k] += xs[k][c] * w;
        }
        if (j < 384) {
#pragma unroll
            for (int k = 0; k < 16; ++k) offs_s[k][col] = acc[k];
        } else {
#pragma unroll
            for (int k = 0; k < 16; ++k) attn_s[k][col] = acc[k];
        }
    }
    __syncthreads();

    // phase 3: softmax over 12 points per (query, head); 256 tasks == 256 threads
    {
        const int qq = t >> 4, h = t & 15;
        float m = -1e30f;
#pragma unroll
        for (int k = 0; k < 12; ++k) m = fmaxf(m, attn_s[qq][h * 12 + k]);
        float s = 0.f;
#pragma unroll
        for (int k = 0; k < 12; ++k) {
            const float e = __expf(attn_s[qq][h * 12 + k] - m);
            attn_s[qq][h * 12 + k] = e;
            s += e;
        }
        const float inv = 1.f / s;
#pragma unroll
        for (int k = 0; k < 12; ++k) attn_s[qq][h * 12 + k] *= inv;
    }
    __syncthreads();

    // phase 4: bilinear sampling; 16q x 16h x 8d = 2048 outputs
    for (int i = t; i < 16 * NH * DH; i += 256) {
        const int qq = i >> 7;
        const int rest = i & 127;
        const int h = rest >> 3;
        const int d = rest & 7;
        const int gq = gq0 + qq;
        const int b = gq / LQ;
        const int q = gq - b * LQ;
        int lq, p, Hq, Wq, startq, wshift;
        q_to_level(q, lq, p, Hq, Wq, startq, wshift);
        const int py = p >> wshift;
        const int px = p & (Wq - 1);
        const float refx = (px + 0.5f) / Wq;
        const float refy = (py + 0.5f) / Hq;
        const size_t vbase = ((size_t)b * LQ) * DM + h * DH + d;
        float acc = 0.f;
#pragma unroll
        for (int l = 0; l < NL; ++l) {
            const int Wl = 64 >> l;
            const int Hl = 64 >> l;
            const int start_l = (l == 0) ? 0 : ((l == 1) ? 4096 : 5120);
            const float invW = 1.f / Wl;
            const float invH = 1.f / Hl;
#pragma unroll
            for (int pt = 0; pt < NP; ++pt) {
                const int ob = ((h * NL + l) * NP + pt) * 2;
                const float ox = offs_s[qq][ob + 0];
                const float oy = offs_s[qq][ob + 1];
                const float a = attn_s[qq][h * 12 + l * NP + pt];
                const float fx = (refx + ox * invW) * Wl - 0.5f;
                const float fy = (refy + oy * invH) * Hl - 0.5f;
                const float x0f = floorf(fx);
                const float y0f = floorf(fy);
                const int x0 = (int)x0f;
                const int y0 = (int)y0f;
                const float fx1 = fx - x0f, fx0 = 1.f - fx1;
                const float fy1 = fy - y0f, fy0 = 1.f - fy1;
#pragma unroll
                for (int dy = 0; dy < 2; ++dy) {
#pragma unroll
                    for (int dx = 0; dx < 2; ++dx) {
                        const int xi = x0 + dx;
                        const int yi = y0 + dy;
                        if (xi >= 0 && xi < Wl && yi >= 0 && yi < Hl) {
                            const float w = (dx ? fx1 : fx0) * (dy ? fy1 : fy0) * a;
                            acc += w * val[vbase + (size_t)(start_l + yi * Wl + xi) * DM];
                        }
                    }
                }
            }
        }
        oh[qq][h * DH + d] = acc;
    }
    __syncthreads();

    // phase 5+6: out = oh @ W_out + b_out, scatter to (B,128,H,W) layout
    {
        const int j  = t & 127;
        const int qb = (t >> 7) * 8;
        float acc[8];
        const float bj = b_out[j];
#pragma unroll
        for (int k = 0; k < 8; ++k) acc[k] = bj;
        for (int c = 0; c < DM; ++c) {
            const float w = W_out[c * DM + j];
#pragma unroll
            for (int k = 0; k < 8; ++k) acc[k] += oh[qb + k][c] * w;
        }
        const size_t lvl_base[3] = {0, 4194304, 5242880};
#pragma unroll
        for (int k = 0; k < 8; ++k) {
            const int gq = gq0 + qb + k;
            const int b = gq / LQ;
            const int q = gq - b * LQ;
            int lq, p, Hq, Wq, startq, wshift;
            q_to_level(q, lq, p, Hq, Wq, startq, wshift);
            const int HWq = Hq * Wq;
            out[lvl_base[lq] + ((size_t)(b * DM + j)) * HWq + p] = acc[k];
        }
    }
}

extern "C" void kernel_launch(void* const* d_in, const int* in_sizes, int n_in,
                              void* d_out, int out_size, void* d_ws, size_t ws_size,
                              hipStream_t stream) {
    const float* fm1    = (const float*)d_in[0];
    const float* fm2    = (const float*)d_in[1];
    const float* fm3    = (const float*)d_in[2];
    const float* W_off  = (const float*)d_in[3];
    const float* b_off  = (const float*)d_in[4];
    const float* W_attn = (const float*)d_in[5];
    const float* b_attn = (const float*)d_in[6];
    const float* W_val  = (const float*)d_in[7];
    const float* b_val  = (const float*)d_in[8];
    const float* W_out  = (const float*)d_in[9];
    const float* b_out  = (const float*)d_in[10];
    float* out = (float*)d_out;

    float* x   = (float*)d_ws;                        // 43008*128 floats = 22 MB
    float* val = x + (size_t)43008 * DM;              // 22 MB

    dim3 tb(32, 8);
    transpose_k<<<dim3(128, 4, 8), tb, 0, stream>>>(fm1, x, 4096, 0);
    transpose_k<<<dim3(32, 4, 8), tb, 0, stream>>>(fm2, x, 1024, 4096);
    transpose_k<<<dim3(8, 4, 8), tb, 0, stream>>>(fm3, x, 256, 5120);

    value_proj_k<<<1344, 256, 0, stream>>>(x, W_val, b_val, val);

    msda_main_k<<<2688, 256, 0, stream>>>(x, val, W_off, b_off, W_attn, b_attn,
                                          W_out, b_out, out);
}

// Round 2
// 369.376 us; speedup vs baseline: 1.7634x; 1.7634x over previous
//
#include <hip/hip_runtime.h>

#define LQ 5376
#define DM 128
#define NH 16
#define NL 3
#define NP 4
#define DH 8

typedef __attribute__((ext_vector_type(8))) short short8;
typedef __attribute__((ext_vector_type(4))) float float4_t;

__device__ __forceinline__ unsigned short f2bf(float f) {
    unsigned u = __builtin_bit_cast(unsigned, f);
    unsigned r = (u + 0x7fffu + ((u >> 16) & 1u)) >> 16;
    return (unsigned short)r;
}
__device__ __forceinline__ float bf2f(unsigned short h) {
    return __builtin_bit_cast(float, (unsigned)h << 16);
}

__device__ __forceinline__ void q_to_level(int q, int& l, int& p, int& Hl, int& Wl,
                                           int& wshift) {
    if (q < 4096)      { l = 0; p = q;        Hl = 64; Wl = 64; wshift = 6; }
    else if (q < 5120) { l = 1; p = q - 4096; Hl = 32; Wl = 32; wshift = 5; }
    else               { l = 2; p = q - 5120; Hl = 16; Wl = 16; wshift = 4; }
}

// ---------------- kernel: transpose weights into [col][k] bf16 (hi/lo for val/out) ----
__global__ __launch_bounds__(256) void convw_k(const float* __restrict__ Wv,
                                               const float* __restrict__ Wo,
                                               const float* __restrict__ Wa,
                                               const float* __restrict__ Wout,
                                               unsigned short* __restrict__ Wvh,
                                               unsigned short* __restrict__ Wvl,
                                               unsigned short* __restrict__ Woa,
                                               unsigned short* __restrict__ Wouth,
                                               unsigned short* __restrict__ Woutl) {
    int idx = blockIdx.x * 256 + threadIdx.x;
    if (idx >= 832 * 128) return;
    int col = idx >> 7;
    int k   = idx & 127;
    if (col < 128) {
        float v = Wv[k * 128 + col];
        unsigned short h = f2bf(v);
        Wvh[col * 128 + k] = h;
        Wvl[col * 128 + k] = f2bf(v - bf2f(h));
    } else if (col < 512) {
        int c = col - 128;
        Woa[c * 128 + k] = f2bf(Wo[k * 384 + c]);
    } else if (col < 704) {
        int c = col - 512;
        Woa[(384 + c) * 128 + k] = f2bf(Wa[k * 192 + c]);
    } else {
        int c = col - 704;
        float v = Wout[k * 128 + c];
        unsigned short h = f2bf(v);
        Wouth[c * 128 + k] = h;
        Woutl[c * 128 + k] = f2bf(v - bf2f(h));
    }
}

// ---------------- kernel: (B,128,HW) -> x rows (B*LQ,128) bf16 hi/lo ----------------
__global__ __launch_bounds__(256) void transpose_k(const float* __restrict__ fm,
                                                   unsigned short* __restrict__ xh,
                                                   unsigned short* __restrict__ xl,
                                                   int HW, int qstart) {
    __shared__ float tile[32][33];
    const int p0 = blockIdx.x * 32;
    const int c0 = blockIdx.y * 32;
    const int b  = blockIdx.z;
    const int tx = threadIdx.x;  // 32
    const int ty = threadIdx.y;  // 8
    const float* src = fm + ((size_t)(b * DM + c0)) * HW + p0;
#pragma unroll
    for (int k = 0; k < 32; k += 8)
        tile[ty + k][tx] = src[(size_t)(ty + k) * HW + tx];
    __syncthreads();
    const size_t dbase = ((size_t)(b * LQ + qstart + p0)) * DM + c0;
#pragma unroll
    for (int k = 0; k < 32; k += 8) {
        float v = tile[tx][ty + k];
        unsigned short h = f2bf(v);
        xh[dbase + (size_t)(ty + k) * DM + tx] = h;
        xl[dbase + (size_t)(ty + k) * DM + tx] = f2bf(v - bf2f(h));
    }
}

// ---------------- kernel: value = x @ W_val + b_val (hi/lo MFMA, bf16 out) ----------
__global__ __launch_bounds__(256) void value_proj_mfma(const unsigned short* __restrict__ xh,
                                                       const unsigned short* __restrict__ xl,
                                                       const unsigned short* __restrict__ Wvh,
                                                       const unsigned short* __restrict__ Wvl,
                                                       const float* __restrict__ b_val,
                                                       unsigned short* __restrict__ valb) {
    const int t = threadIdx.x;
    const int wv = t >> 6;
    const int lane = t & 63;
    const int m = lane & 15, quad = lane >> 4;
    const int q0 = blockIdx.x * 64 + wv * 16;

    short8 ah[4], al[4];
    const size_t arow = (size_t)(q0 + m) * DM;
#pragma unroll
    for (int kk = 0; kk < 4; ++kk) {
        ah[kk] = *(const short8*)(xh + arow + kk * 32 + quad * 8);
        al[kk] = *(const short8*)(xl + arow + kk * 32 + quad * 8);
    }
    float4_t acc[8];
#pragma unroll
    for (int tt = 0; tt < 8; ++tt) acc[tt] = (float4_t)(0.f);
#pragma unroll
    for (int tt = 0; tt < 8; ++tt) {
        const size_t brow = (size_t)(tt * 16 + m) * DM;
#pragma unroll
        for (int kk = 0; kk < 4; ++kk) {
            short8 bh = *(const short8*)(Wvh + brow + kk * 32 + quad * 8);
            short8 bl = *(const short8*)(Wvl + brow + kk * 32 + quad * 8);
            acc[tt] = __builtin_amdgcn_mfma_f32_16x16x32_bf16(ah[kk], bh, acc[tt], 0, 0, 0);
            acc[tt] = __builtin_amdgcn_mfma_f32_16x16x32_bf16(al[kk], bh, acc[tt], 0, 0, 0);
            acc[tt] = __builtin_amdgcn_mfma_f32_16x16x32_bf16(ah[kk], bl, acc[tt], 0, 0, 0);
        }
    }
#pragma unroll
    for (int tt = 0; tt < 8; ++tt) {
        const int col = tt * 16 + m;
        const float bb = b_val[col];
#pragma unroll
        for (int r = 0; r < 4; ++r) {
            const int row = quad * 4 + r;
            valb[(size_t)(q0 + row) * DM + col] = f2bf(acc[tt][r] + bb);
        }
    }
}

// ---------------- mega kernel: coef MFMA + softmax + sampling + out MFMA ------------
__global__ __launch_bounds__(256) void sampler_k(const unsigned short* __restrict__ xh,
                                                 const unsigned short* __restrict__ valb,
                                                 const unsigned short* __restrict__ Woa,
                                                 const float* __restrict__ b_off,
                                                 const float* __restrict__ b_attn,
                                                 const unsigned short* __restrict__ Wouth,
                                                 const unsigned short* __restrict__ Woutl,
                                                 const float* __restrict__ b_out,
                                                 float* __restrict__ out) {
    __shared__ float coef[16][580];  // cols 0..383 offs, 384..575 attn logits->probs
    __shared__ float oh[16][132];
    const int t = threadIdx.x;
    const int wv = t >> 6;
    const int lane = t & 63;
    const int m = lane & 15, quad = lane >> 4;
    const int gq0 = blockIdx.x * 16;

    // ---- phase A: coef = x @ [W_off|W_attn] (bf16 MFMA), 36 col-tiles over 4 waves
    {
        short8 af[4];
        const size_t arow = (size_t)(gq0 + m) * DM;
#pragma unroll
        for (int kk = 0; kk < 4; ++kk)
            af[kk] = *(const short8*)(xh + arow + kk * 32 + quad * 8);
        float4_t acc[9];
#pragma unroll
        for (int tt = 0; tt < 9; ++tt) acc[tt] = (float4_t)(0.f);
#pragma unroll
        for (int tt = 0; tt < 9; ++tt) {
            const size_t brow = (size_t)((wv * 9 + tt) * 16 + m) * DM;
#pragma unroll
            for (int kk = 0; kk < 4; ++kk) {
                short8 bf = *(const short8*)(Woa + brow + kk * 32 + quad * 8);
                acc[tt] = __builtin_amdgcn_mfma_f32_16x16x32_bf16(af[kk], bf, acc[tt], 0, 0, 0);
            }
        }
#pragma unroll
        for (int tt = 0; tt < 9; ++tt) {
            const int col = (wv * 9 + tt) * 16 + m;
            const float bb = (col < 384) ? b_off[col] : b_attn[col - 384];
#pragma unroll
            for (int r = 0; r < 4; ++r)
                coef[quad * 4 + r][col] = acc[tt][r] + bb;
        }
    }
    __syncthreads();

    // ---- phase B: softmax over 12 pts per (query, head)
    {
        const int qq = t >> 4, h = t & 15;
        float* a = &coef[qq][384 + h * 12];
        float mx = -1e30f;
#pragma unroll
        for (int k = 0; k < 12; ++k) mx = fmaxf(mx, a[k]);
        float s = 0.f;
#pragma unroll
        for (int k = 0; k < 12; ++k) {
            const float e = __expf(a[k] - mx);
            a[k] = e;
            s += e;
        }
        const float inv = 1.f / s;
#pragma unroll
        for (int k = 0; k < 12; ++k) a[k] *= inv;
    }
    __syncthreads();

    // ---- phase C: bilinear sampling (bf16 value, 2 channels/lane)
#pragma unroll
    for (int it = 0; it < 4; ++it) {
        const int i = it * 256 + t;
        const int qq = i >> 6;
        const int rest = i & 63;
        const int h = rest >> 2;
        const int d2 = rest & 3;
        const int gq = gq0 + qq;
        const int b = gq / LQ;
        const int q = gq - b * LQ;
        int lq, p, Hq, Wq, wshift;
        q_to_level(q, lq, p, Hq, Wq, wshift);
        const int py = p >> wshift;
        const int px = p & (Wq - 1);
        const float refx = (px + 0.5f) / Wq;
        const float refy = (py + 0.5f) / Hq;
        const unsigned short* vrow = valb + ((size_t)b * LQ) * DM + h * DH + d2 * 2;
        float accx = 0.f, accy = 0.f;
#pragma unroll
        for (int l = 0; l < NL; ++l) {
            const int Wl = 64 >> l;
            const int Hl = 64 >> l;
            const int start_l = (l == 0) ? 0 : ((l == 1) ? 4096 : 5120);
#pragma unroll
            for (int pt = 0; pt < NP; ++pt) {
                const float ox = coef[qq][(h * NL + l) * (NP * 2) + pt * 2 + 0];
                const float oy = coef[qq][(h * NL + l) * (NP * 2) + pt * 2 + 1];
                const float a = coef[qq][384 + h * 12 + l * NP + pt];
                const float fx = refx * Wl + ox - 0.5f;
                const float fy = refy * Hl + oy - 0.5f;
                const float x0f = floorf(fx);
                const float y0f = floorf(fy);
                const int x0 = (int)x0f;
                const int y0 = (int)y0f;
                const float fx1 = fx - x0f, fx0c = 1.f - fx1;
                const float fy1 = fy - y0f, fy0c = 1.f - fy1;
#pragma unroll
                for (int dy = 0; dy < 2; ++dy) {
#pragma unroll
                    for (int dx = 0; dx < 2; ++dx) {
                        const int xi = x0 + dx;
                        const int yi = y0 + dy;
                        if (xi >= 0 && xi < Wl && yi >= 0 && yi < Hl) {
                            const float w = (dx ? fx1 : fx0c) * (dy ? fy1 : fy0c) * a;
                            const unsigned pv = *(const unsigned*)(vrow +
                                (size_t)(start_l + yi * Wl + xi) * DM);
                            accx += w * __builtin_bit_cast(float, pv << 16);
                            accy += w * __builtin_bit_cast(float, pv & 0xffff0000u);
                        }
                    }
                }
            }
        }
        oh[qq][h * DH + d2 * 2 + 0] = accx;
        oh[qq][h * DH + d2 * 2 + 1] = accy;
    }
    __syncthreads();

    // ---- phase D: out = oh @ W_out + b_out (hi/lo MFMA), scatter to (B,128,H,W)
    {
        float4_t acc2[2];
        acc2[0] = (float4_t)(0.f);
        acc2[1] = (float4_t)(0.f);
#pragma unroll
        for (int kk = 0; kk < 4; ++kk) {
            const float4_t a0 = *(const float4_t*)&oh[m][kk * 32 + quad * 8];
            const float4_t a1 = *(const float4_t*)&oh[m][kk * 32 + quad * 8 + 4];
            short8 ahi, alo;
#pragma unroll
            for (int j = 0; j < 8; ++j) {
                const float f = (j < 4) ? a0[j] : a1[j - 4];
                const unsigned short h = f2bf(f);
                ahi[j] = (short)h;
                alo[j] = (short)f2bf(f - bf2f(h));
            }
#pragma unroll
            for (int tt = 0; tt < 2; ++tt) {
                const size_t brow = (size_t)((wv * 2 + tt) * 16 + m) * DM;
                short8 bh = *(const short8*)(Wouth + brow + kk * 32 + quad * 8);
                short8 bl = *(const short8*)(Woutl + brow + kk * 32 + quad * 8);
                acc2[tt] = __builtin_amdgcn_mfma_f32_16x16x32_bf16(ahi, bh, acc2[tt], 0, 0, 0);
                acc2[tt] = __builtin_amdgcn_mfma_f32_16x16x32_bf16(alo, bh, acc2[tt], 0, 0, 0);
                acc2[tt] = __builtin_amdgcn_mfma_f32_16x16x32_bf16(ahi, bl, acc2[tt], 0, 0, 0);
            }
        }
        const size_t lvl_base[3] = {0, 4194304, 5242880};
#pragma unroll
        for (int tt = 0; tt < 2; ++tt) {
            const int col = (wv * 2 + tt) * 16 + m;
            const float bb = b_out[col];
#pragma unroll
            for (int r = 0; r < 4; ++r) {
                const int qq = quad * 4 + r;
                const int gq = gq0 + qq;
                const int b = gq / LQ;
                const int q = gq - b * LQ;
                int lq, p, Hq, Wq, wshift;
                q_to_level(q, lq, p, Hq, Wq, wshift);
                const int HWq = Hq * Wq;
                out[lvl_base[lq] + ((size_t)(b * DM + col)) * HWq + p] = acc2[tt][r] + bb;
            }
        }
    }
}

extern "C" void kernel_launch(void* const* d_in, const int* in_sizes, int n_in,
                              void* d_out, int out_size, void* d_ws, size_t ws_size,
                              hipStream_t stream) {
    const float* fm1    = (const float*)d_in[0];
    const float* fm2    = (const float*)d_in[1];
    const float* fm3    = (const float*)d_in[2];
    const float* W_off  = (const float*)d_in[3];
    const float* b_off  = (const float*)d_in[4];
    const float* W_attn = (const float*)d_in[5];
    const float* b_attn = (const float*)d_in[6];
    const float* W_val  = (const float*)d_in[7];
    const float* b_val  = (const float*)d_in[8];
    const float* W_out  = (const float*)d_in[9];
    const float* b_out  = (const float*)d_in[10];
    float* out = (float*)d_out;

    const size_t NQ = (size_t)8 * LQ;          // 43008
    unsigned short* xh   = (unsigned short*)d_ws;            // 11,010,048 B
    unsigned short* xl   = xh + NQ * DM;                     // 11,010,048 B
    unsigned short* valb = xl + NQ * DM;                     // 11,010,048 B
    unsigned short* Wvh  = valb + NQ * DM;                   // 32768 B
    unsigned short* Wvl  = Wvh + 128 * 128;
    unsigned short* Woa  = Wvl + 128 * 128;                  // 147456 B
    unsigned short* Wouth= Woa + 576 * 128;
    unsigned short* Woutl= Wouth + 128 * 128;

    convw_k<<<416, 256, 0, stream>>>(W_val, W_off, W_attn, W_out,
                                     Wvh, Wvl, Woa, Wouth, Woutl);

    dim3 tb(32, 8);
    transpose_k<<<dim3(128, 4, 8), tb, 0, stream>>>(fm1, xh, xl, 4096, 0);
    transpose_k<<<dim3(32, 4, 8), tb, 0, stream>>>(fm2, xh, xl, 1024, 4096);
    transpose_k<<<dim3(8, 4, 8), tb, 0, stream>>>(fm3, xh, xl, 256, 5120);

    value_proj_mfma<<<672, 256, 0, stream>>>(xh, xl, Wvh, Wvl, b_val, valb);

    sampler_k<<<2688, 256, 0, stream>>>(xh, valb, Woa, b_off, b_attn,
                                        Wouth, Woutl, b_out, out);
}

// Round 3
// 300.032 us; speedup vs baseline: 2.1710x; 1.2311x over previous
//
#include <hip/hip_runtime.h>

#define LQ 5376
#define DM 128
#define NH 16
#define NL 3
#define NP 4
#define DH 8

typedef __attribute__((ext_vector_type(8))) short short8;
typedef __attribute__((ext_vector_type(4))) float float4_t;
typedef __attribute__((ext_vector_type(4))) unsigned int uint4_t;

__device__ __forceinline__ unsigned short f2bf(float f) {
    unsigned u = __builtin_bit_cast(unsigned, f);
    unsigned r = (u + 0x7fffu + ((u >> 16) & 1u)) >> 16;
    return (unsigned short)r;
}
__device__ __forceinline__ float bf2f(unsigned short h) {
    return __builtin_bit_cast(float, (unsigned)h << 16);
}

__device__ __forceinline__ void q_to_level(int q, int& l, int& p, int& Hl, int& Wl,
                                           int& wshift) {
    if (q < 4096)      { l = 0; p = q;        Hl = 64; Wl = 64; wshift = 6; }
    else if (q < 5120) { l = 1; p = q - 4096; Hl = 32; Wl = 32; wshift = 5; }
    else               { l = 2; p = q - 5120; Hl = 16; Wl = 16; wshift = 4; }
}

// ---- weights -> [col][k] bf16 (hi/lo only for W_out; W_val plain bf16) ----
__global__ __launch_bounds__(256) void convw_k(const float* __restrict__ Wv,
                                               const float* __restrict__ Wo,
                                               const float* __restrict__ Wa,
                                               const float* __restrict__ Wout,
                                               unsigned short* __restrict__ Wvh,
                                               unsigned short* __restrict__ Woa,
                                               unsigned short* __restrict__ Wouth,
                                               unsigned short* __restrict__ Woutl) {
    int idx = blockIdx.x * 256 + threadIdx.x;
    if (idx >= 832 * 128) return;
    int col = idx >> 7;
    int k   = idx & 127;
    if (col < 128) {
        Wvh[col * 128 + k] = f2bf(Wv[k * 128 + col]);
    } else if (col < 512) {
        int c = col - 128;
        Woa[c * 128 + k] = f2bf(Wo[k * 384 + c]);
    } else if (col < 704) {
        int c = col - 512;
        Woa[(384 + c) * 128 + k] = f2bf(Wa[k * 192 + c]);
    } else {
        int c = col - 704;
        float v = Wout[k * 128 + c];
        unsigned short h = f2bf(v);
        Wouth[c * 128 + k] = h;
        Woutl[c * 128 + k] = f2bf(v - bf2f(h));
    }
}

// ---- (B,128,HW) -> x rows (B*LQ,128) bf16 ----
__global__ __launch_bounds__(256) void transpose_k(const float* __restrict__ fm,
                                                   unsigned short* __restrict__ xh,
                                                   int HW, int qstart) {
    __shared__ float tile[32][33];
    const int p0 = blockIdx.x * 32;
    const int c0 = blockIdx.y * 32;
    const int b  = blockIdx.z;
    const int tx = threadIdx.x;  // 32
    const int ty = threadIdx.y;  // 8
    const float* src = fm + ((size_t)(b * DM + c0)) * HW + p0;
#pragma unroll
    for (int k = 0; k < 32; k += 8)
        tile[ty + k][tx] = src[(size_t)(ty + k) * HW + tx];
    __syncthreads();
    const size_t dbase = ((size_t)(b * LQ + qstart + p0)) * DM + c0;
#pragma unroll
    for (int k = 0; k < 32; k += 8)
        xh[dbase + (size_t)(ty + k) * DM + tx] = f2bf(tile[tx][ty + k]);
}

// ---- value = x @ W_val + b_val (bf16 MFMA), repack to head-major valh ----
// valh layout: [(h*8 + b) * LQ + pos] * 8 channels (bf16), 16 B per (h,b,pos)
__global__ __launch_bounds__(256) void value_proj_mfma(const unsigned short* __restrict__ xh,
                                                       const unsigned short* __restrict__ Wvh,
                                                       const float* __restrict__ b_val,
                                                       unsigned short* __restrict__ valh) {
    __shared__ unsigned short vs[64][136];
    const int t = threadIdx.x;
    const int wv = t >> 6;
    const int lane = t & 63;
    const int m = lane & 15, quad = lane >> 4;
    const int q0 = blockIdx.x * 64 + wv * 16;

    short8 ah[4];
    const size_t arow = (size_t)(q0 + m) * DM;
#pragma unroll
    for (int kk = 0; kk < 4; ++kk)
        ah[kk] = *(const short8*)(xh + arow + kk * 32 + quad * 8);
    float4_t acc[8];
#pragma unroll
    for (int tt = 0; tt < 8; ++tt) acc[tt] = (float4_t)(0.f);
#pragma unroll
    for (int tt = 0; tt < 8; ++tt) {
        const size_t brow = (size_t)(tt * 16 + m) * DM;
#pragma unroll
        for (int kk = 0; kk < 4; ++kk) {
            short8 bh = *(const short8*)(Wvh + brow + kk * 32 + quad * 8);
            acc[tt] = __builtin_amdgcn_mfma_f32_16x16x32_bf16(ah[kk], bh, acc[tt], 0, 0, 0);
        }
    }
#pragma unroll
    for (int tt = 0; tt < 8; ++tt) {
        const int col = tt * 16 + m;
        const float bb = b_val[col];
#pragma unroll
        for (int r = 0; r < 4; ++r)
            vs[wv * 16 + quad * 4 + r][col] = f2bf(acc[tt][r] + bb);
    }
    __syncthreads();

    const int bq = blockIdx.x * 64;        // 64 queries, never spans a batch
    const int b = bq / LQ;
    const int pos0 = bq - b * LQ;
    const int h  = t >> 4;
    const int ql = t & 15;
#pragma unroll
    for (int it = 0; it < 4; ++it) {
        const int qloc = it * 16 + ql;
        uint4_t v = *(const uint4_t*)&vs[qloc][h * 8];
        *(uint4_t*)(valh + ((size_t)(h * 8 + b) * LQ + pos0 + qloc) * 8) = v;
    }
}

// ---- mega kernel: coef MFMA + softmax + sampling + out MFMA ----
__global__ __launch_bounds__(256) void sampler_k(const unsigned short* __restrict__ xh,
                                                 const unsigned short* __restrict__ valh,
                                                 const unsigned short* __restrict__ Woa,
                                                 const float* __restrict__ b_off,
                                                 const float* __restrict__ b_attn,
                                                 const unsigned short* __restrict__ Wouth,
                                                 const unsigned short* __restrict__ Woutl,
                                                 const float* __restrict__ b_out,
                                                 float* __restrict__ out) {
    __shared__ float coef[16][16][37];  // [q][h][0..23 offs, 24..35 attn], stride 37
    __shared__ float oh[16][132];
    const int t = threadIdx.x;
    const int wv = t >> 6;
    const int lane = t & 63;
    const int m = lane & 15, quad = lane >> 4;
    const int gq0 = blockIdx.x * 16;

    // ---- phase A: [offs|attn] = x @ Woa (bf16 MFMA), 36 col-tiles over 4 waves
    {
        short8 af[4];
        const size_t arow = (size_t)(gq0 + m) * DM;
#pragma unroll
        for (int kk = 0; kk < 4; ++kk)
            af[kk] = *(const short8*)(xh + arow + kk * 32 + quad * 8);
        float4_t acc[9];
#pragma unroll
        for (int tt = 0; tt < 9; ++tt) acc[tt] = (float4_t)(0.f);
#pragma unroll
        for (int tt = 0; tt < 9; ++tt) {
            const size_t brow = (size_t)((wv * 9 + tt) * 16 + m) * DM;
#pragma unroll
            for (int kk = 0; kk < 4; ++kk) {
                short8 bf = *(const short8*)(Woa + brow + kk * 32 + quad * 8);
                acc[tt] = __builtin_amdgcn_mfma_f32_16x16x32_bf16(af[kk], bf, acc[tt], 0, 0, 0);
            }
        }
#pragma unroll
        for (int tt = 0; tt < 9; ++tt) {
            const int col = (wv * 9 + tt) * 16 + m;
            int hc, jc;
            float bb;
            if (col < 384) { hc = col / 24; jc = col - hc * 24; bb = b_off[col]; }
            else { int cc = col - 384; hc = cc / 12; jc = 24 + cc - hc * 12; bb = b_attn[cc]; }
#pragma unroll
            for (int r = 0; r < 4; ++r)
                coef[quad * 4 + r][hc][jc] = acc[tt][r] + bb;
        }
    }
    __syncthreads();

    // ---- phase B: softmax over 12 pts per (query, head)
    {
        float* a = &coef[t >> 4][t & 15][24];
        float mx = -1e30f;
#pragma unroll
        for (int k = 0; k < 12; ++k) mx = fmaxf(mx, a[k]);
        float s = 0.f;
#pragma unroll
        for (int k = 0; k < 12; ++k) {
            const float e = __expf(a[k] - mx);
            a[k] = e;
            s += e;
        }
        const float inv = 1.f / s;
#pragma unroll
        for (int k = 0; k < 12; ++k) a[k] *= inv;
    }
    __syncthreads();

    // ---- phase C: bilinear sampling, one thread per (q,h), dwordx4 corners
    {
        const int qq = t >> 4;
        const int h  = t & 15;
        const int gq = gq0 + qq;
        const int b  = gq / LQ;
        const int q  = gq - b * LQ;
        int lq, p, Hq, Wq, wshift;
        q_to_level(q, lq, p, Hq, Wq, wshift);
        const float refx = ((p & (Wq - 1)) + 0.5f) / Wq;
        const float refy = ((p >> wshift) + 0.5f) / Hq;
        const float* cf = &coef[qq][h][0];
        const unsigned short* vbase = valh + ((size_t)(h * 8 + b) * LQ) * 8;
        float acc[8];
#pragma unroll
        for (int e = 0; e < 8; ++e) acc[e] = 0.f;
#pragma unroll
        for (int l = 0; l < NL; ++l) {
            const int Wl = 64 >> l;
            const int Hl = Wl;
            const int start_l = (l == 0) ? 0 : ((l == 1) ? 4096 : 5120);
            const float fxb = refx * Wl - 0.5f;
            const float fyb = refy * Hl - 0.5f;
#pragma unroll
            for (int pt = 0; pt < NP; ++pt) {
                const float ox = cf[(l * NP + pt) * 2 + 0];
                const float oy = cf[(l * NP + pt) * 2 + 1];
                const float a  = cf[24 + l * NP + pt];
                const float fx = fxb + ox;
                const float fy = fyb + oy;
                const float x0f = floorf(fx);
                const float y0f = floorf(fy);
                const int x0 = (int)x0f;
                const int y0 = (int)y0f;
                const float fx1 = fx - x0f, fy1 = fy - y0f;
                const float gx0 = (x0 >= 0 && x0 < Wl)          ? (1.f - fx1) : 0.f;
                const float gx1 = (x0 >= -1 && x0 < Wl - 1)     ? fx1 : 0.f;
                const float gy0 = (y0 >= 0 && y0 < Hl)          ? (1.f - fy1) : 0.f;
                const float gy1 = (y0 >= -1 && y0 < Hl - 1)     ? fy1 : 0.f;
                const int xc0 = min(max(x0, 0), Wl - 1);
                const int xc1 = min(max(x0 + 1, 0), Wl - 1);
                const int yc0 = min(max(y0, 0), Hl - 1);
                const int yc1 = min(max(y0 + 1, 0), Hl - 1);
                const int r0 = start_l + yc0 * Wl;
                const int r1 = start_l + yc1 * Wl;
                const uint4_t v00 = *(const uint4_t*)(vbase + (size_t)(r0 + xc0) * 8);
                const uint4_t v01 = *(const uint4_t*)(vbase + (size_t)(r0 + xc1) * 8);
                const uint4_t v10 = *(const uint4_t*)(vbase + (size_t)(r1 + xc0) * 8);
                const uint4_t v11 = *(const uint4_t*)(vbase + (size_t)(r1 + xc1) * 8);
                const float w00 = gx0 * gy0 * a;
                const float w01 = gx1 * gy0 * a;
                const float w10 = gx0 * gy1 * a;
                const float w11 = gx1 * gy1 * a;
#pragma unroll
                for (int dd = 0; dd < 4; ++dd) {
                    acc[dd * 2 + 0] += w00 * __builtin_bit_cast(float, v00[dd] << 16)
                                    +  w01 * __builtin_bit_cast(float, v01[dd] << 16)
                                    +  w10 * __builtin_bit_cast(float, v10[dd] << 16)
                                    +  w11 * __builtin_bit_cast(float, v11[dd] << 16);
                    acc[dd * 2 + 1] += w00 * __builtin_bit_cast(float, v00[dd] & 0xffff0000u)
                                    +  w01 * __builtin_bit_cast(float, v01[dd] & 0xffff0000u)
                                    +  w10 * __builtin_bit_cast(float, v10[dd] & 0xffff0000u)
                                    +  w11 * __builtin_bit_cast(float, v11[dd] & 0xffff0000u);
                }
            }
        }
#pragma unroll
        for (int e = 0; e < 8; ++e) oh[qq][h * 8 + e] = acc[e];
    }
    __syncthreads();

    // ---- phase D: out = oh @ W_out + b_out (hi/lo MFMA), scatter to (B,128,H,W)
    {
        float4_t acc2[2];
        acc2[0] = (float4_t)(0.f);
        acc2[1] = (float4_t)(0.f);
#pragma unroll
        for (int kk = 0; kk < 4; ++kk) {
            const float4_t a0 = *(const float4_t*)&oh[m][kk * 32 + quad * 8];
            const float4_t a1 = *(const float4_t*)&oh[m][kk * 32 + quad * 8 + 4];
            short8 ahi, alo;
#pragma unroll
            for (int j = 0; j < 8; ++j) {
                const float f = (j < 4) ? a0[j] : a1[j - 4];
                const unsigned short h = f2bf(f);
                ahi[j] = (short)h;
                alo[j] = (short)f2bf(f - bf2f(h));
            }
#pragma unroll
            for (int tt = 0; tt < 2; ++tt) {
                const size_t brow = (size_t)((wv * 2 + tt) * 16 + m) * DM;
                short8 bh = *(const short8*)(Wouth + brow + kk * 32 + quad * 8);
                short8 bl = *(const short8*)(Woutl + brow + kk * 32 + quad * 8);
                acc2[tt] = __builtin_amdgcn_mfma_f32_16x16x32_bf16(ahi, bh, acc2[tt], 0, 0, 0);
                acc2[tt] = __builtin_amdgcn_mfma_f32_16x16x32_bf16(alo, bh, acc2[tt], 0, 0, 0);
                acc2[tt] = __builtin_amdgcn_mfma_f32_16x16x32_bf16(ahi, bl, acc2[tt], 0, 0, 0);
            }
        }
        const size_t lvl_base[3] = {0, 4194304, 5242880};
#pragma unroll
        for (int tt = 0; tt < 2; ++tt) {
            const int col = (wv * 2 + tt) * 16 + m;
            const float bb = b_out[col];
#pragma unroll
            for (int r = 0; r < 4; ++r) {
                const int qq = quad * 4 + r;
                const int gq = gq0 + qq;
                const int b = gq / LQ;
                const int q = gq - b * LQ;
                int lq, p, Hq, Wq, wshift;
                q_to_level(q, lq, p, Hq, Wq, wshift);
                const int HWq = Hq * Wq;
                out[lvl_base[lq] + ((size_t)(b * DM + col)) * HWq + p] = acc2[tt][r] + bb;
            }
        }
    }
}

extern "C" void kernel_launch(void* const* d_in, const int* in_sizes, int n_in,
                              void* d_out, int out_size, void* d_ws, size_t ws_size,
                              hipStream_t stream) {
    const float* fm1    = (const float*)d_in[0];
    const float* fm2    = (const float*)d_in[1];
    const float* fm3    = (const float*)d_in[2];
    const float* W_off  = (const float*)d_in[3];
    const float* b_off  = (const float*)d_in[4];
    const float* W_attn = (const float*)d_in[5];
    const float* b_attn = (const float*)d_in[6];
    const float* W_val  = (const float*)d_in[7];
    const float* b_val  = (const float*)d_in[8];
    const float* W_out  = (const float*)d_in[9];
    const float* b_out  = (const float*)d_in[10];
    float* out = (float*)d_out;

    const size_t NQ = (size_t)8 * LQ;          // 43008
    unsigned short* xh    = (unsigned short*)d_ws;      // 11,010,048 B
    unsigned short* valh  = xh + NQ * DM;               // 11,010,048 B (head-major)
    unsigned short* Wvh   = valh + NQ * DM;             // 32 KB
    unsigned short* Woa   = Wvh + 128 * 128;            // 144 KB
    unsigned short* Wouth = Woa + 576 * 128;
    unsigned short* Woutl = Wouth + 128 * 128;

    convw_k<<<416, 256, 0, stream>>>(W_val, W_off, W_attn, W_out,
                                     Wvh, Woa, Wouth, Woutl);

    dim3 tb(32, 8);
    transpose_k<<<dim3(128, 4, 8), tb, 0, stream>>>(fm1, xh, 4096, 0);
    transpose_k<<<dim3(32, 4, 8), tb, 0, stream>>>(fm2, xh, 1024, 4096);
    transpose_k<<<dim3(8, 4, 8), tb, 0, stream>>>(fm3, xh, 256, 5120);

    value_proj_mfma<<<672, 256, 0, stream>>>(xh, Wvh, b_val, valh);

    sampler_k<<<2688, 256, 0, stream>>>(xh, valh, Woa, b_off, b_attn,
                                        Wouth, Woutl, b_out, out);
}